// Round 10
// baseline (193.744 us; speedup 1.0000x reference)
//
#include <hip/hip_runtime.h>
#include <hip/hip_bf16.h>

typedef __attribute__((ext_vector_type(8))) short bf16x8;
typedef __attribute__((ext_vector_type(4))) float f32x4;

static __device__ __forceinline__ unsigned short f2bf(float f) {
    unsigned u = __builtin_bit_cast(unsigned, f);
    unsigned rounding = 0x7fffu + ((u >> 16) & 1u);
    u += rounding;
    return (unsigned short)(u >> 16);
}

static __device__ __forceinline__ void async_copy16(const void* g, void* l) {
    __builtin_amdgcn_global_load_lds(
        (const __attribute__((address_space(1))) unsigned int*)g,
        (__attribute__((address_space(3))) unsigned int*)l,
        16, 0, 0);
}

#define BARRIER() __builtin_amdgcn_s_barrier()
#define VMCNT(N) do { asm volatile("s_waitcnt vmcnt(" #N ")" ::: "memory"); \
                      __builtin_amdgcn_sched_barrier(0); } while (0)

// fast erf-gelu via tanh approximation (|err| <= ~3e-3, threshold margin 0.07+)
static __device__ __forceinline__ float fast_gelu(float y) {
    float u = 0.7978845608028654f * y * (1.0f + 0.044715f * y * y);
    float au = fminf(fabsf(u), 9.0f);
    float e = __expf(-2.0f * au);
    float th = (1.0f - e) * __builtin_amdgcn_rcpf(1.0f + e);
    th = (u < 0.0f) ? -th : th;
    return 0.5f * y * (1.0f + th);
}

// ---------------- LayerNorm (fp32) -> bf16 cast ----------------
__global__ __launch_bounds__(256) void ln_cast_kernel(
    const float* __restrict__ x, const float* __restrict__ gamma,
    const float* __restrict__ beta, unsigned short* __restrict__ out) {
    const int row = blockIdx.x;
    const int t = threadIdx.x;
    const float4 v = ((const float4*)(x + (size_t)row * 1024))[t];

    float s  = v.x + v.y + v.z + v.w;
    float ss = v.x * v.x + v.y * v.y + v.z * v.z + v.w * v.w;
    #pragma unroll
    for (int off = 32; off; off >>= 1) {
        s  += __shfl_down(s, off);
        ss += __shfl_down(ss, off);
    }
    __shared__ float red[8];
    const int wid = t >> 6, lane = t & 63;
    if (lane == 0) { red[wid] = s; red[wid + 4] = ss; }
    __syncthreads();
    if (t == 0) {
        float S  = red[0] + red[1] + red[2] + red[3];
        float SS = red[4] + red[5] + red[6] + red[7];
        float mu = S * (1.0f / 1024.0f);
        float var = SS * (1.0f / 1024.0f) - mu * mu;
        red[0] = mu;
        red[1] = rsqrtf(var + 1e-7f);
    }
    __syncthreads();
    const float mu = red[0], rs = red[1];
    const float4 g = ((const float4*)gamma)[t];
    const float4 b = ((const float4*)beta)[t];

    ushort4 pk;
    pk.x = f2bf((v.x - mu) * rs * g.x + b.x);
    pk.y = f2bf((v.y - mu) * rs * g.y + b.y);
    pk.z = f2bf((v.z - mu) * rs * g.z + b.z);
    pk.w = f2bf((v.w - mu) * rs * g.w + b.w);
    ((ushort4*)(out + (size_t)row * 1024))[t] = pk;
}

// ---------------- W [1024][4096] fp32 -> Wt [4096][1024] bf16 ----------------
__global__ __launch_bounds__(256) void wt_cast_kernel(
    const float* __restrict__ W, unsigned short* __restrict__ Wt) {
    __shared__ float tile[32][33];
    const int bx = blockIdx.x;
    const int by = blockIdx.y;
    const int tx = threadIdx.x & 31;
    const int ty = threadIdx.x >> 5;
    #pragma unroll
    for (int i = 0; i < 4; ++i) {
        int k = by * 32 + ty + i * 8;
        tile[ty + i * 8][tx] = W[(size_t)k * 4096 + bx * 32 + tx];
    }
    __syncthreads();
    #pragma unroll
    for (int i = 0; i < 4; ++i) {
        int n = bx * 32 + ty + i * 8;
        Wt[(size_t)n * 1024 + by * 32 + tx] = f2bf(tile[tx][ty + i * 8]);
    }
}

// ---------------- GEMM 256x256 tile, BK=32, TRIPLE-buffered LDS (96KB) ---------
// 8 waves (2M x 4N), wave 128x64. Stage 2 K-tiles ahead into buf[(kt+2)%3]
// (race-free: that buffer's reads finished before the previous barrier).
// End-of-iter wait is counted vmcnt(4) -> loads never drain to 0 in the loop.
// LDS per buf: A 256 rows x 64B (16KB) + B 16KB. R4-verified conflict-free
// layout: 64B rows, chunk swizzle slot = c ^ ((row>>1)&3), linear gload dest.
__global__ __launch_bounds__(512, 2) void gemm_kernel(
    const unsigned short* __restrict__ A, const unsigned short* __restrict__ Wt,
    const float* __restrict__ bias, float* __restrict__ out) {
    __shared__ char lds_mem[98304];   // 3 bufs x 32KB

    const int bid = blockIdx.x;                 // 1024 blocks, %8==0 -> bijective
    const int swz = (bid & 7) * 128 + (bid >> 3);
    const int bm = swz >> 4;                    // 0..63
    const int bn = swz & 15;                    // 0..15

    const int t = threadIdx.x;
    const int lane = t & 63;
    const int wid = t >> 6;                     // 0..7
    const int wm = wid >> 2;                    // 0..1  (M half)
    const int wn = wid & 3;                     // 0..3  (N quarter)
    const int lrow = lane & 15;
    const int lk = lane >> 4;                   // 0..3

    // staging: thread t owns A slots {t, t+512}, B slots {t, t+512}.
    // slot s: row s>>2, lds chunk s&3, global chunk (s&3)^((s>>3)&3)
    const int srr = t >> 2;                     // 0..127  (2nd A slot: +128)
    const int sgc = (t & 3) ^ ((t >> 3) & 3);
    const unsigned short* gA = A  + (size_t)(bm * 256 + srr) * 1024 + sgc * 8;
    const unsigned short* gB = Wt + (size_t)(bn * 256 + srr) * 1024 + sgc * 8;
    const int lslot = t * 16;

    auto stage = [&](int kt, char* buf) {
        async_copy16(gA + kt * 32,                      buf + lslot);
        async_copy16(gA + (size_t)128 * 1024 + kt * 32, buf + 8192  + lslot);
        async_copy16(gB + kt * 32,                      buf + 16384 + lslot);
        async_copy16(gB + (size_t)128 * 1024 + kt * 32, buf + 24576 + lslot);
    };

    // read side: frag row R (R&7 == lrow&7 pattern irrelevant here): 64B rows,
    // chunk lk at slot lk ^ ((R>>1)&3); (R>>1)&3 == (lrow>>1)&3 (16/64/128 mult off)
    const int swzc = (lk ^ ((lrow >> 1) & 3)) * 16;
    const int aOff = (wm * 128 + lrow) * 64 + swzc;          // + mi*16*64, mi 0..7
    const int bOff = 16384 + (wn * 64 + lrow) * 64 + swzc;   // + ni*16*64, ni 0..3

    f32x4 acc[8][4];
    #pragma unroll
    for (int i = 0; i < 8; ++i)
        #pragma unroll
        for (int j = 0; j < 4; ++j) acc[i][j] = (f32x4)0.0f;

    float bv[4];
    #pragma unroll
    for (int ni = 0; ni < 4; ++ni) bv[ni] = bias[bn * 256 + wn * 64 + ni * 16 + lrow];

    // prologue: kt0 -> buf0, kt1 -> buf1; wait kt0 (4 newest outstanding = kt1)
    stage(0, lds_mem);
    stage(1, lds_mem + 32768);
    VMCNT(4);
    BARRIER();

    const int NKT = 32;
    int cb = 0;   // kt % 3
    for (int kt = 0; kt < NKT; ++kt) {
        char* cbuf = lds_mem + cb * 32768;

        // stage kt+2 into buf[(kt+2)%3] == buf[(cb+2)%3]: its readers finished
        // before the previous barrier -> race-free by ordering alone.
        if (kt + 2 < NKT) {
            char* sbuf = lds_mem + ((cb >= 1) ? (cb - 1) : 2) * 32768;
            stage(kt + 2, sbuf);
        }

        // B frags (4 reads, live across mi loop)
        bf16x8 bf[4];
        #pragma unroll
        for (int ni = 0; ni < 4; ++ni)
            bf[ni] = *(const bf16x8*)(cbuf + bOff + ni * 16 * 64);

        // per-mi: 1 A read + 4 MFMA (compiler pipelines lgkmcnt)
        __builtin_amdgcn_s_setprio(1);
        #pragma unroll
        for (int mi = 0; mi < 8; ++mi) {
            bf16x8 a = *(const bf16x8*)(cbuf + aOff + mi * 16 * 64);
            #pragma unroll
            for (int ni = 0; ni < 4; ++ni)
                acc[mi][ni] = __builtin_amdgcn_mfma_f32_16x16x32_bf16(
                    a, bf[ni], acc[mi][ni], 0, 0, 0);
        }
        __builtin_amdgcn_s_setprio(0);

        // counted wait: kt+1's 4 loads landed; kt+2's 4 stay in flight
        if (kt < NKT - 2) {
            VMCNT(4);
            BARRIER();
        } else if (kt == NKT - 2) {
            VMCNT(0);
            BARRIER();
        }
        cb = (cb == 2) ? 0 : cb + 1;
    }

    // ---- epilogue: bias + fast gelu, fp32 store
    #pragma unroll
    for (int mi = 0; mi < 8; ++mi) {
        const int row0 = bm * 256 + wm * 128 + mi * 16 + lk * 4;
        #pragma unroll
        for (int ni = 0; ni < 4; ++ni) {
            const int col = bn * 256 + wn * 64 + ni * 16 + lrow;
            #pragma unroll
            for (int r = 0; r < 4; ++r) {
                float y = acc[mi][ni][r] + bv[ni];
                out[(size_t)(row0 + r) * 4096 + col] = fast_gelu(y);
            }
        }
    }
}

extern "C" void kernel_launch(void* const* d_in, const int* in_sizes, int n_in,
                              void* d_out, int out_size, void* d_ws, size_t ws_size,
                              hipStream_t stream) {
    const float* hidden = (const float*)d_in[0];
    const float* gamma  = (const float*)d_in[1];
    const float* beta   = (const float*)d_in[2];
    const float* W      = (const float*)d_in[3];
    const float* bias   = (const float*)d_in[4];
    float* out = (float*)d_out;

    unsigned short* Abf = (unsigned short*)d_ws;
    unsigned short* Wt  = (unsigned short*)((char*)d_ws + (size_t)16384 * 1024 * 2);

    ln_cast_kernel<<<16384, 256, 0, stream>>>(hidden, gamma, beta, Abf);
    wt_cast_kernel<<<dim3(128, 32), 256, 0, stream>>>(W, Wt);
    gemm_kernel<<<1024, 512, 0, stream>>>(Abf, Wt, bias, out);
}